// Round 2
// baseline (7634.750 us; speedup 1.0000x reference)
//
#include <hip/hip_runtime.h>
#include <cstdint>
#include <cstddef>

// Problem constants
#define Hh 2048
#define Vv 32000
#define Bb 16
#define Ss 256

typedef unsigned short ushort_t;
typedef unsigned int   uint_t;

typedef __attribute__((ext_vector_type(8))) short short8;   // 8 x bf16 (4 VGPRs)
typedef __attribute__((ext_vector_type(4))) float f32x4;    // MFMA accumulator

// ---- workspace layout (bytes) ----
// Zbuf : [buf2][b][h] bf16  z~ = exp(y - chunkmax)      131,072
// pmax : [g8][k256][wl32][c2] f32 chunk maxes           524,288
// cnt  : [g8][k256] u32 barrier counters                  8,192
// Y255 : [b][h] f32 final-step y (f32)                  131,072
#define Z_OFF    0ull
#define Z_BYTES  ((size_t)2 * Bb * Hh * 2)
#define PM_OFF   (Z_OFF + Z_BYTES)
#define PM_BYTES ((size_t)8 * 256 * 32 * 2 * 4)
#define CNT_OFF  (PM_OFF + PM_BYTES)
#define CNT_BYTES ((size_t)8 * 256 * 4)
#define Y_OFF    (CNT_OFF + CNT_BYTES)
#define Y_BYTES  ((size_t)Bb * Hh * 4)
#define WS_NEED  (Y_OFF + Y_BYTES)

__device__ __forceinline__ ushort_t f2b(float f) {
  union { float f; uint_t u; } x; x.f = f;
  uint_t u = x.u;
  return (ushort_t)((u + 0x7FFFu + ((u >> 16) & 1u)) >> 16);   // RNE f32->bf16
}

// ---------------------------------------------------------------------------
// Persistent scan kernel. 256 WGs x 256 threads, launched cooperatively.
// 8 independent column-groups (g = blockIdx & 7) of 32 WGs; group g owns
// batch columns {2g, 2g+1} (groups never communicate; under round-robin
// block->XCD mapping a group is XCD-local — speed heuristic only).
// WG wl owns rows [wl*64, wl*64+64); each of its 4 waves holds 16 alpha rows
// as register-resident bf16 MFMA A-fragments (64 x short8 = 256 VGPRs),
// converted from f32 once.
// Per step k: group barrier -> global col max from 32 chunk maxes ->
// rescale producer z~ into LDS (bf16) -> 64 x mfma 16x16x32 bf16 (lanes with
// col>=2 alias col&1 in LDS = free broadcast; results ignored) ->
// y = log(sum) + m + ip (ip prefetched one step ahead from beta) ->
// write ys (f32 out), z~^(k), chunk max -> fence -> atomic arrive.
// ---------------------------------------------------------------------------
__global__ __launch_bounds__(256, 1) void hmm_persist(
    const float* __restrict__ alpha,
    const float* __restrict__ beta,
    const int*  __restrict__ ids,
    ushort_t* __restrict__ Zbuf,
    float* __restrict__ pmax,
    uint_t* __restrict__ cnt,
    float* __restrict__ Y255,
    float* __restrict__ out)
{
  const int w    = blockIdx.x;
  const int g    = w & 7;
  const int wl   = w >> 3;         // 0..31 within group -> row chunk
  const int c0   = g * 2;          // first batch column of group
  const int tid  = threadIdx.x;
  const int wv   = tid >> 6;       // wave 0..3
  const int lane = tid & 63;
  const int lrow = lane & 15;
  const int quad = lane >> 4;
  const int r0   = wl * 64 + wv * 16;

  __shared__ __align__(16) ushort_t zTf[2 * 2080];  // 2 cols x (2048+32 pad)
  __shared__ float pmv[64];
  __shared__ float scl[2][32];
  __shared__ float red[4][2];
  __shared__ float mchunk[2];
  __shared__ float ybuf[128];
  __shared__ float ipld[128];      // ip_rev[k] for this WG: [rr 0..63][c 0..1]

  // ---- preload alpha A-fragments (rows r0..r0+15, K=2048), f32 -> bf16 ----
  short8 afr[64];
  {
    const float* arow = alpha + (size_t)(r0 + lrow) * Hh + quad * 8;
    #pragma unroll
    for (int kt = 0; kt < 64; ++kt) {
      short8 fr;
      #pragma unroll
      for (int j = 0; j < 8; ++j) fr[j] = (short)f2b(arow[kt * 32 + j]);
      afr[kt] = fr;
    }
  }

  uint_t* mycnt = cnt + g * 256;
  const int myc = tid & 1;                 // gather mapping for tid<128
  const int myr = wl * 64 + (tid >> 1);
  float ipreg = 0.f;

  // ---- init: y^(0) = ip_rev[0] = beta[:, ids[:, S-1]]; publish z~^(0) ----
  {
    float yv = 0.f;
    if (tid < 128) {
      const int v = ids[(c0 + myc) * Ss + (Ss - 1)];
      yv = beta[(size_t)myr * Vv + v];
      ybuf[tid] = yv;
      out[(size_t)myr * Bb + (c0 + myc)] = yv;   // ys[0][h][b]
    }
    __syncthreads();
    if (tid < 2) {
      float mm = -3.0e38f;
      for (int j = 0; j < 64; ++j) mm = fmaxf(mm, ybuf[2 * j + tid]);
      mchunk[tid] = mm;
      pmax[((size_t)(g * 256 + 0) * 32 + wl) * 2 + tid] = mm;
    }
    __syncthreads();
    if (tid < 128) {
      Zbuf[(size_t)(c0 + myc) * Hh + myr] = f2b(__expf(yv - mchunk[myc]));
      // prefetch ip_rev[1]
      const int v1 = ids[(c0 + myc) * Ss + (Ss - 2)];
      ipreg = beta[(size_t)myr * Vv + v1];
    }
    __threadfence();
    __syncthreads();
    if (tid == 0)
      __hip_atomic_fetch_add(mycnt + 0, 1u, __ATOMIC_RELEASE, __HIP_MEMORY_SCOPE_AGENT);
  }

  const ushort_t* zbase = zTf + (lrow & 1) * 2080 + quad * 8;  // col>=2 aliases col&1

  for (int k = 1; k < Ss; ++k) {
    const int zb = (k - 1) & 1;

    // ---- S1: all 32 group WGs published step k-1 ----
    if (tid == 0) {
      while (__hip_atomic_load(mycnt + (k - 1), __ATOMIC_ACQUIRE, __HIP_MEMORY_SCOPE_AGENT) != 32u)
        __builtin_amdgcn_s_sleep(1);
    }
    __syncthreads();

    // ---- global col max over 32 chunk maxes; per-chunk rescale factors ----
    if (tid < 64)
      pmv[tid] = pmax[((size_t)(g * 256 + (k - 1)) * 32 + (tid >> 1)) * 2 + (tid & 1)];
    __syncthreads();                                   // S2
    float m0 = -3.0e38f, m1 = -3.0e38f;
    for (int j = 0; j < 32; ++j) {
      m0 = fmaxf(m0, pmv[2 * j]);
      m1 = fmaxf(m1, pmv[2 * j + 1]);
    }
    if (tid < 64) scl[tid & 1][tid >> 1] = __expf(pmv[tid] - ((tid & 1) ? m1 : m0));
    __syncthreads();                                   // S3

    // ---- stage z = z~ * scale into LDS (bf16); land this step's ip ----
    {
      const ushort_t* zsrc = Zbuf + (size_t)zb * Bb * Hh;
      for (int i = tid; i < 2048; i += 256) {
        const int c = i >> 10;
        const int h = (i & 1023) * 2;
        uint_t zz = *(const uint_t*)(zsrc + (size_t)(c0 + c) * Hh + h);
        float s  = scl[c][h >> 6];
        float z0, z1;
        { union { uint_t u; float f; } x0, x1;
          x0.u = (zz & 0xFFFFu) << 16;  x1.u = zz & 0xFFFF0000u;
          z0 = x0.f * s; z1 = x1.f * s; }
        *(uint_t*)(zTf + c * 2080 + h) = (uint_t)f2b(z0) | ((uint_t)f2b(z1) << 16);
      }
      if (tid < 128) ipld[tid] = ipreg;
    }
    __syncthreads();                                   // S4

    // ---- prefetch ip_rev[k+1] (consumed next step; ~1 step of latency) ----
    if (k < Ss - 1 && tid < 128) {
      const int v = ids[(c0 + myc) * Ss + (Ss - 2 - k)];
      ipreg = beta[(size_t)myr * Vv + v];
    }

    // ---- MFMA K-loop: D = alpha_rows @ z  (8 independent acc chains) ----
    f32x4 acc[8];
    {
      f32x4 zv = {0.f, 0.f, 0.f, 0.f};
      #pragma unroll
      for (int j = 0; j < 8; ++j) acc[j] = zv;
    }
    #pragma unroll
    for (int kt = 0; kt < 64; ++kt) {
      short8 bfr = *(const short8*)(zbase + kt * 32);
      acc[kt & 7] = __builtin_amdgcn_mfma_f32_16x16x32_bf16(afr[kt], bfr, acc[kt & 7], 0, 0, 0);
    }
    f32x4 sf = ((acc[0] + acc[1]) + (acc[2] + acc[3])) +
               ((acc[4] + acc[5]) + (acc[6] + acc[7]));

    // ---- epilogue: y = log(D) + m + ip_rev[k]; publish ----
    const int  c   = lrow;                 // D col = batch col (C/D: col=lane&15)
    const int  rb  = r0 + quad * 4;        // D rows = quad*4 + reg
    const int  lrr = wv * 16 + quad * 4;   // row index within WG chunk
    const bool act = (lrow < 2);
    const float mc = (lrow & 1) ? m1 : m0;
    float yv4[4];
    float lm = -3.0e38f;
    if (act) {
      #pragma unroll
      for (int i = 0; i < 4; ++i) {
        float yv = __logf(sf[i]) + mc + ipld[(lrr + i) * 2 + c];
        yv4[i] = yv;
        lm = fmaxf(lm, yv);
        out[(size_t)k * (Hh * Bb) + (size_t)(rb + i) * Bb + (c0 + c)] = yv;
      }
    }
    lm = fmaxf(lm, __shfl_xor(lm, 16));
    lm = fmaxf(lm, __shfl_xor(lm, 32));
    if (lane < 2) red[wv][lane] = lm;
    __syncthreads();                                   // S5
    if (tid < 2) {
      float mm = fmaxf(fmaxf(red[0][tid], red[1][tid]), fmaxf(red[2][tid], red[3][tid]));
      mchunk[tid] = mm;
      pmax[((size_t)(g * 256 + k) * 32 + wl) * 2 + tid] = mm;
    }
    __syncthreads();                                   // S6
    if (act) {
      const float mchc = mchunk[c];
      uint2 pk;
      pk.x = (uint_t)f2b(__expf(yv4[0] - mchc)) | ((uint_t)f2b(__expf(yv4[1] - mchc)) << 16);
      pk.y = (uint_t)f2b(__expf(yv4[2] - mchc)) | ((uint_t)f2b(__expf(yv4[3] - mchc)) << 16);
      *(uint2*)(Zbuf + ((size_t)(k & 1) * Bb + (c0 + c)) * Hh + rb) = pk;
      if (k == Ss - 1) {
        float4 yo; yo.x = yv4[0]; yo.y = yv4[1]; yo.z = yv4[2]; yo.w = yv4[3];
        *(float4*)(Y255 + (size_t)(c0 + c) * Hh + rb) = yo;
      }
    }
    __threadfence();
    __syncthreads();                                   // S7
    if (tid == 0)
      __hip_atomic_fetch_add(mycnt + k, 1u, __ATOMIC_RELEASE, __HIP_MEMORY_SCOPE_AGENT);
  }
}

// ---------------------------------------------------------------------------
// final[b] = log(sum_h e^{(g[h]-gm)+(y[h]-ym)}) - log(sum_h e^{g[h]-gm}) + ym
// ---------------------------------------------------------------------------
__global__ __launch_bounds__(256) void final_k(
    const float* __restrict__ gamma, const float* __restrict__ Y255,
    float* __restrict__ out)
{
  const int b = blockIdx.x;
  const int tid = threadIdx.x;
  __shared__ float sb[256];

  float ym = -3.0e38f;
  for (int h = tid; h < Hh; h += 256) ym = fmaxf(ym, Y255[(size_t)b * Hh + h]);
  sb[tid] = ym; __syncthreads();
  for (int off = 128; off; off >>= 1) {
    if (tid < off) sb[tid] = fmaxf(sb[tid], sb[tid + off]);
    __syncthreads();
  }
  ym = sb[0]; __syncthreads();

  float gm = -3.0e38f;
  for (int h = tid; h < Hh; h += 256) gm = fmaxf(gm, gamma[h]);
  sb[tid] = gm; __syncthreads();
  for (int off = 128; off; off >>= 1) {
    if (tid < off) sb[tid] = fmaxf(sb[tid], sb[tid + off]);
    __syncthreads();
  }
  gm = sb[0]; __syncthreads();

  float s1 = 0.f, s2 = 0.f;
  for (int h = tid; h < Hh; h += 256) {
    float gv = gamma[h] - gm;
    s1 += __expf(gv);
    s2 += __expf(gv + Y255[(size_t)b * Hh + h] - ym);
  }
  sb[tid] = s1; __syncthreads();
  for (int off = 128; off; off >>= 1) {
    if (tid < off) sb[tid] += sb[tid + off];
    __syncthreads();
  }
  s1 = sb[0]; __syncthreads();
  sb[tid] = s2; __syncthreads();
  for (int off = 128; off; off >>= 1) {
    if (tid < off) sb[tid] += sb[tid + off];
    __syncthreads();
  }
  s2 = sb[0];

  if (tid == 0)
    out[(size_t)Ss * Hh * Bb + b] = __logf(s2) - __logf(s1) + ym;
}

// ---------------------------------------------------------------------------
extern "C" void kernel_launch(void* const* d_in, const int* in_sizes, int n_in,
                              void* d_out, int out_size, void* d_ws, size_t ws_size,
                              hipStream_t stream) {
  (void)in_sizes; (void)n_in; (void)out_size;
  const int*   ids   = (const int*)d_in[0];
  const float* alpha = (const float*)d_in[1];
  const float* beta  = (const float*)d_in[2];
  const float* gamma = (const float*)d_in[3];
  float* out = (float*)d_out;
  char* ws = (char*)d_ws;

  if (ws_size < WS_NEED) return;   // clean fail rather than OOB

  ushort_t* Zbuf = (ushort_t*)(ws + Z_OFF);
  float*    pmax = (float*)(ws + PM_OFF);
  uint_t*   cnt  = (uint_t*)(ws + CNT_OFF);
  float*    Y255 = (float*)(ws + Y_OFF);

  hipMemsetAsync(cnt, 0, CNT_BYTES, stream);

  {
    const float* a_alpha = alpha;
    const float* a_beta  = beta;
    const int*   a_ids   = ids;
    ushort_t* a_z = Zbuf;  float* a_pm = pmax;  uint_t* a_cnt = cnt;
    float* a_y = Y255;     float* a_out = out;
    void* args[] = {(void*)&a_alpha, (void*)&a_beta, (void*)&a_ids, (void*)&a_z,
                    (void*)&a_pm, (void*)&a_cnt, (void*)&a_y, (void*)&a_out};
    hipError_t e = hipLaunchCooperativeKernel((const void*)hmm_persist,
                                              dim3(256), dim3(256), args, 0, stream);
    if (e != hipSuccess) {
      // fallback: plain launch; 256 WGs at >=1 WG/CU on 256 CUs are co-resident
      hipLaunchKernelGGL(hmm_persist, dim3(256), dim3(256), 0, stream,
                         alpha, beta, ids, Zbuf, pmax, cnt, Y255, out);
    }
  }

  hipLaunchKernelGGL(final_k, dim3(Bb), dim3(256), 0, stream, gamma, Y255, out);
}

// Round 3
// 1569.182 us; speedup vs baseline: 4.8654x; 4.8654x over previous
//
#include <hip/hip_runtime.h>
#include <cstdint>
#include <cstddef>

// Problem constants
#define Hh 2048
#define Vv 32000
#define Bb 16
#define Ss 256

typedef unsigned short ushort_t;
typedef unsigned int   uint_t;
typedef unsigned long long ull_t;

typedef __attribute__((ext_vector_type(8))) short short8;   // 8 x bf16 (4 VGPRs)
typedef __attribute__((ext_vector_type(4))) float f32x4;    // MFMA accumulator

// ---- workspace layout (bytes) ----
// Zbuf : [buf2][b][h] bf16  z~ = exp(y - chunkmax)      131,072
// pmax : [g8][k256][wl32][c2] f32 chunk maxes           524,288
// cnt  : [g8][k256] u32 barrier counters                  8,192
// Y255 : [b][h] f32 final-step y                        131,072
#define Z_OFF    0ull
#define Z_BYTES  ((size_t)2 * Bb * Hh * 2)
#define PM_OFF   (Z_OFF + Z_BYTES)
#define PM_BYTES ((size_t)8 * 256 * 32 * 2 * 4)
#define CNT_OFF  (PM_OFF + PM_BYTES)
#define CNT_BYTES ((size_t)8 * 256 * 4)
#define Y_OFF    (CNT_OFF + CNT_BYTES)
#define Y_BYTES  ((size_t)Bb * Hh * 4)
#define WS_NEED  (Y_OFF + Y_BYTES)

// Relaxed agent-scope atomics: plain sc1 loads/stores, NO buffer_inv/buffer_wbl2.
// Visibility protocol: producer sc1-stores -> __syncthreads (drains vmcnt(0)
// per wave, so stores are acked at the coherence point) -> tid0 relaxed
// fetch_add. Consumer relaxed-polls the counter, then relaxed-loads data that
// is already at the coherence point. No fences anywhere in the hot loop.
#define LD_REL(p)     __hip_atomic_load((p), __ATOMIC_RELAXED, __HIP_MEMORY_SCOPE_AGENT)
#define ST_REL(p, v)  __hip_atomic_store((p), (v), __ATOMIC_RELAXED, __HIP_MEMORY_SCOPE_AGENT)
#define ADD_REL(p)    __hip_atomic_fetch_add((p), 1u, __ATOMIC_RELAXED, __HIP_MEMORY_SCOPE_AGENT)

__device__ __forceinline__ float b2f_u(uint_t u) {
  union { uint_t u; float f; } x; x.u = u; return x.f;
}
__device__ __forceinline__ ushort_t f2b(float f) {
  union { float f; uint_t u; } x; x.f = f;
  uint_t u = x.u;
  return (ushort_t)((u + 0x7FFFu + ((u >> 16) & 1u)) >> 16);   // RNE f32->bf16
}

// ---------------------------------------------------------------------------
// Persistent scan kernel. 256 WGs x 256 threads.
// 8 independent column-groups (g = blockIdx & 7) of 32 WGs; group g owns
// batch columns {2g, 2g+1}. WG wl owns rows [wl*64, wl*64+64); each of its
// 4 waves holds 16 alpha rows as register-resident bf16 A-fragments
// (64 x short8 = 256 VGPRs), converted from f32 once.
// ---------------------------------------------------------------------------
__global__ __launch_bounds__(256, 1) void hmm_persist(
    const float* __restrict__ alpha,
    const float* __restrict__ beta,
    const int*  __restrict__ ids,
    ushort_t* __restrict__ Zbuf,
    float* __restrict__ pmax,
    uint_t* __restrict__ cnt,
    float* __restrict__ Y255,
    float* __restrict__ out)
{
  const int w    = blockIdx.x;
  const int g    = w & 7;
  const int wl   = w >> 3;         // 0..31 within group -> row chunk
  const int c0   = g * 2;          // first batch column of group
  const int tid  = threadIdx.x;
  const int wv   = tid >> 6;       // wave 0..3
  const int lane = tid & 63;
  const int lrow = lane & 15;
  const int quad = lane >> 4;
  const int r0   = wl * 64 + wv * 16;

  __shared__ __align__(16) ushort_t zTf[2 * 2080];  // 2 cols x (2048+32 pad)
  __shared__ float sclL[64];       // [c][chunk32] rescale factors
  __shared__ float m01[2];         // global col maxes (also chunkmax in init)
  __shared__ float red[4][2];
  __shared__ float ybuf[128];
  __shared__ float ipld[128];      // ip_rev[k] for this WG: [rr][c]

  ull_t* Zb64 = (ull_t*)Zbuf;
  uint_t* Zb32 = (uint_t*)Zbuf;

  // ---- preload alpha A-fragments (rows r0..r0+15, K=2048), f32 -> bf16 ----
  short8 afr[64];
  {
    const float* arow = alpha + (size_t)(r0 + lrow) * Hh + quad * 8;
    #pragma unroll
    for (int kt = 0; kt < 64; ++kt) {
      float4 f0 = *(const float4*)(arow + kt * 32);
      float4 f1 = *(const float4*)(arow + kt * 32 + 4);
      short8 fr;
      fr[0] = (short)f2b(f0.x); fr[1] = (short)f2b(f0.y);
      fr[2] = (short)f2b(f0.z); fr[3] = (short)f2b(f0.w);
      fr[4] = (short)f2b(f1.x); fr[5] = (short)f2b(f1.y);
      fr[6] = (short)f2b(f1.z); fr[7] = (short)f2b(f1.w);
      afr[kt] = fr;
    }
  }

  uint_t* mycnt = cnt + g * 256;
  const int myc = tid & 1;                 // gather mapping for tid<128
  const int myr = wl * 64 + (tid >> 1);
  float ipreg = 0.f;

  // ---- init: y^(0) = ip_rev[0] = beta[:, ids[:, S-1]]; publish z~^(0) ----
  {
    float yv = 0.f;
    if (tid < 128) {
      const int v = ids[(c0 + myc) * Ss + (Ss - 1)];
      yv = beta[(size_t)myr * Vv + v];
      ybuf[tid] = yv;
      out[(size_t)myr * Bb + (c0 + myc)] = yv;   // ys[0][h][b]
    }
    __syncthreads();
    if (tid < 2) {
      float mm = -3.0e38f;
      for (int j = 0; j < 64; ++j) mm = fmaxf(mm, ybuf[2 * j + tid]);
      m01[tid] = mm;
      ST_REL(pmax + (size_t)(g * 256 + 0) * 64 + wl * 2 + tid, mm);
    }
    __syncthreads();
    if (tid < 64) {
      const int c = tid >> 5, rr0 = (tid & 31) * 2;
      const float mm = m01[c];
      uint_t lo = f2b(__expf(ybuf[rr0 * 2 + c] - mm));
      uint_t hi = f2b(__expf(ybuf[rr0 * 2 + 2 + c] - mm));
      ST_REL(Zb32 + (size_t)(c0 + c) * 1024 + (wl * 32 + (tid & 31)),
             lo | (hi << 16));
    }
    if (tid < 128) {   // prefetch ip_rev[1]
      const int v1 = ids[(c0 + myc) * Ss + (Ss - 2)];
      ipreg = beta[(size_t)myr * Vv + v1];
    }
    __syncthreads();   // drains the sc1 stores (vmcnt(0) before s_barrier)
    if (tid == 0) ADD_REL(mycnt + 0);
  }

  const ushort_t* zbase = zTf + (lrow & 1) * 2080 + quad * 8;  // col>=2 aliases col&1

  for (int k = 1; k < Ss; ++k) {
    const int zb = (k - 1) & 1;

    // ---- S1: all 32 group WGs published step k-1 (relaxed poll, no inv) ----
    if (tid == 0) {
      while (LD_REL(mycnt + (k - 1)) != 32u) { }
    }
    __syncthreads();

    // ---- issue Zbuf loads immediately (overlap with pmax RTT) ----
    ull_t zr[4];
    {
      const size_t zB = (size_t)zb * 16 * 512;
      #pragma unroll
      for (int j = 0; j < 4; ++j) {
        const int idx = j * 256 + tid;        // 0..1023 ull over 2 cols
        const int c = idx >> 9;
        const int h4 = idx & 511;
        zr[j] = LD_REL(Zb64 + zB + (size_t)(c0 + c) * 512 + h4);
      }
    }

    // ---- wave0: pmax -> global col maxes + rescale factors (shfl only) ----
    if (tid < 64) {
      float pv = LD_REL(pmax + (size_t)(g * 256 + (k - 1)) * 64 + tid);
      float mr = pv;   // parity-preserving butterfly -> per-col max
      mr = fmaxf(mr, __shfl_xor(mr, 2));
      mr = fmaxf(mr, __shfl_xor(mr, 4));
      mr = fmaxf(mr, __shfl_xor(mr, 8));
      mr = fmaxf(mr, __shfl_xor(mr, 16));
      mr = fmaxf(mr, __shfl_xor(mr, 32));
      sclL[(tid & 1) * 32 + (tid >> 1)] = __expf(pv - mr);
      if (tid < 2) m01[tid] = mr;
    }
    __syncthreads();                                   // S3

    // ---- stage z = z~ * scale into LDS (bf16); land this step's ip ----
    {
      #pragma unroll
      for (int j = 0; j < 4; ++j) {
        const int idx = j * 256 + tid;
        const int c = idx >> 9;
        const int h = (idx & 511) * 4;
        const float s = sclL[c * 32 + (h >> 6)];
        const ull_t u = zr[j];
        const uint_t lo = (uint_t)u, hi = (uint_t)(u >> 32);
        float z0 = b2f_u((lo & 0xFFFFu) << 16) * s;
        float z1 = b2f_u(lo & 0xFFFF0000u) * s;
        float z2 = b2f_u((hi & 0xFFFFu) << 16) * s;
        float z3 = b2f_u(hi & 0xFFFF0000u) * s;
        uint_t o0 = (uint_t)f2b(z0) | ((uint_t)f2b(z1) << 16);
        uint_t o1 = (uint_t)f2b(z2) | ((uint_t)f2b(z3) << 16);
        *(ull_t*)(zTf + c * 2080 + h) = (ull_t)o0 | ((ull_t)o1 << 32);
      }
      if (tid < 128) ipld[tid] = ipreg;
    }
    __syncthreads();                                   // S4

    // ---- prefetch ip_rev[k+1] (overlapped with MFMA) ----
    if (k < Ss - 1 && tid < 128) {
      const int v = ids[(c0 + myc) * Ss + (Ss - 2 - k)];
      ipreg = beta[(size_t)myr * Vv + v];
    }

    // ---- MFMA K-loop: D = alpha_rows @ z  (8 independent acc chains) ----
    f32x4 acc[8];
    {
      f32x4 zv = {0.f, 0.f, 0.f, 0.f};
      #pragma unroll
      for (int j = 0; j < 8; ++j) acc[j] = zv;
    }
    #pragma unroll
    for (int kt = 0; kt < 64; ++kt) {
      short8 bfr = *(const short8*)(zbase + kt * 32);
      acc[kt & 7] = __builtin_amdgcn_mfma_f32_16x16x32_bf16(afr[kt], bfr, acc[kt & 7], 0, 0, 0);
    }
    f32x4 sf = ((acc[0] + acc[1]) + (acc[2] + acc[3])) +
               ((acc[4] + acc[5]) + (acc[6] + acc[7]));

    // ---- epilogue: y = log(D) + m + ip_rev[k] ----
    const int  c   = lrow;                 // D col = batch col
    const int  rb  = r0 + quad * 4;        // D rows = quad*4 + reg
    const int  lrr = wv * 16 + quad * 4;   // row within WG chunk
    const bool act = (lrow < 2);
    const float mc = m01[lrow & 1];
    float yv4[4];
    float lm = -3.0e38f;
    if (act) {
      #pragma unroll
      for (int i = 0; i < 4; ++i) {
        float yv = __logf(sf[i]) + mc + ipld[(lrr + i) * 2 + c];
        yv4[i] = yv;
        lm = fmaxf(lm, yv);
      }
    }
    lm = fmaxf(lm, __shfl_xor(lm, 16));
    lm = fmaxf(lm, __shfl_xor(lm, 32));
    if (lane < 2) red[wv][lane] = lm;
    __syncthreads();                                   // S5

    // ---- publish z~^(k) + chunk max (relaxed sc1 stores) ----
    float mch = 0.f;
    if (act) {
      mch = fmaxf(fmaxf(red[0][c], red[1][c]), fmaxf(red[2][c], red[3][c]));
      uint_t o0 = (uint_t)f2b(__expf(yv4[0] - mch)) | ((uint_t)f2b(__expf(yv4[1] - mch)) << 16);
      uint_t o1 = (uint_t)f2b(__expf(yv4[2] - mch)) | ((uint_t)f2b(__expf(yv4[3] - mch)) << 16);
      ST_REL(Zb64 + ((size_t)(k & 1) * 16 + (c0 + c)) * 512 + (rb >> 2),
             (ull_t)o0 | ((ull_t)o1 << 32));
    }
    if (tid < 2)
      ST_REL(pmax + (size_t)(g * 256 + k) * 64 + wl * 2 + tid, mch);
    __syncthreads();   // S7: drains all waves' sc1 stores (vmcnt(0) at barrier)
    if (tid == 0) ADD_REL(mycnt + k);

    // ---- off critical path: write ys[k] (nobody reads `out` intra-kernel) ----
    if (act) {
      #pragma unroll
      for (int i = 0; i < 4; ++i)
        out[(size_t)k * (Hh * Bb) + (size_t)(rb + i) * Bb + (c0 + c)] = yv4[i];
      if (k == Ss - 1) {
        float4 yo; yo.x = yv4[0]; yo.y = yv4[1]; yo.z = yv4[2]; yo.w = yv4[3];
        *(float4*)(Y255 + (size_t)(c0 + c) * Hh + rb) = yo;
      }
    }
  }
}

// ---------------------------------------------------------------------------
// final[b] = log(sum_h e^{(g[h]-gm)+(y[h]-ym)}) - log(sum_h e^{g[h]-gm}) + ym
// ---------------------------------------------------------------------------
__global__ __launch_bounds__(256) void final_k(
    const float* __restrict__ gamma, const float* __restrict__ Y255,
    float* __restrict__ out)
{
  const int b = blockIdx.x;
  const int tid = threadIdx.x;
  __shared__ float sb[256];

  float ym = -3.0e38f;
  for (int h = tid; h < Hh; h += 256) ym = fmaxf(ym, Y255[(size_t)b * Hh + h]);
  sb[tid] = ym; __syncthreads();
  for (int off = 128; off; off >>= 1) {
    if (tid < off) sb[tid] = fmaxf(sb[tid], sb[tid + off]);
    __syncthreads();
  }
  ym = sb[0]; __syncthreads();

  float gm = -3.0e38f;
  for (int h = tid; h < Hh; h += 256) gm = fmaxf(gm, gamma[h]);
  sb[tid] = gm; __syncthreads();
  for (int off = 128; off; off >>= 1) {
    if (tid < off) sb[tid] = fmaxf(sb[tid], sb[tid + off]);
    __syncthreads();
  }
  gm = sb[0]; __syncthreads();

  float s1 = 0.f, s2 = 0.f;
  for (int h = tid; h < Hh; h += 256) {
    float gv = gamma[h] - gm;
    s1 += __expf(gv);
    s2 += __expf(gv + Y255[(size_t)b * Hh + h] - ym);
  }
  sb[tid] = s1; __syncthreads();
  for (int off = 128; off; off >>= 1) {
    if (tid < off) sb[tid] += sb[tid + off];
    __syncthreads();
  }
  s1 = sb[0]; __syncthreads();
  sb[tid] = s2; __syncthreads();
  for (int off = 128; off; off >>= 1) {
    if (tid < off) sb[tid] += sb[tid + off];
    __syncthreads();
  }
  s2 = sb[0];

  if (tid == 0)
    out[(size_t)Ss * Hh * Bb + b] = __logf(s2) - __logf(s1) + ym;
}

// ---------------------------------------------------------------------------
extern "C" void kernel_launch(void* const* d_in, const int* in_sizes, int n_in,
                              void* d_out, int out_size, void* d_ws, size_t ws_size,
                              hipStream_t stream) {
  (void)in_sizes; (void)n_in; (void)out_size;
  const int*   ids   = (const int*)d_in[0];
  const float* alpha = (const float*)d_in[1];
  const float* beta  = (const float*)d_in[2];
  const float* gamma = (const float*)d_in[3];
  float* out = (float*)d_out;
  char* ws = (char*)d_ws;

  if (ws_size < WS_NEED) return;   // clean fail rather than OOB

  ushort_t* Zbuf = (ushort_t*)(ws + Z_OFF);
  float*    pmax = (float*)(ws + PM_OFF);
  uint_t*   cnt  = (uint_t*)(ws + CNT_OFF);
  float*    Y255 = (float*)(ws + Y_OFF);

  hipMemsetAsync(cnt, 0, CNT_BYTES, stream);

  {
    const float* a_alpha = alpha;
    const float* a_beta  = beta;
    const int*   a_ids   = ids;
    ushort_t* a_z = Zbuf;  float* a_pm = pmax;  uint_t* a_cnt = cnt;
    float* a_y = Y255;     float* a_out = out;
    void* args[] = {(void*)&a_alpha, (void*)&a_beta, (void*)&a_ids, (void*)&a_z,
                    (void*)&a_pm, (void*)&a_cnt, (void*)&a_y, (void*)&a_out};
    hipError_t e = hipLaunchCooperativeKernel((const void*)hmm_persist,
                                              dim3(256), dim3(256), args, 0, stream);
    if (e != hipSuccess) {
      hipLaunchKernelGGL(hmm_persist, dim3(256), dim3(256), 0, stream,
                         alpha, beta, ids, Zbuf, pmax, cnt, Y255, out);
    }
  }

  hipLaunchKernelGGL(final_k, dim3(Bb), dim3(256), 0, stream, gamma, Y255, out);
}